// Round 4
// baseline (337.229 us; speedup 1.0000x reference)
//
#include <hip/hip_runtime.h>
#include <hip/hip_bf16.h>

#define H0 480
#define W0 640
#define H1 240
#define W1 320
#define H2 120
#define W2 160
#define H3 60
#define W3 80

// fp32 weight buffer offsets (in floats) inside d_ws  (transposed pointwise copies)
#define W_PW1T  0      // 5*32  [cin*32+o]
#define W_PW2T  160    // 32*64 [cin*64+o]
#define W_PW3T  2208   // 64*64 [cin*64+o]
#define WBUF_BYTES 65536

#define F2_PB (64 * H2 * W2)   // 1,228,800
#define F3_PB (64 * H3 * W3)   //   307,200

// k_fuse12 tiling: each block computes a 32x8 f2-pixel tile via a shared f1 tile.
#define TH 8           // f2 tile height
#define TW 32          // f2 tile width
#define TILES_W 5      // W2/TW
#define TILES_H 15     // H2/TH
#define TILES_PB 75    // per batch
#define F1COLS 65      // 2*TW+1
#define NP 1105        // 17*65 f1 pixels per tile
#define LROW 66        // swizzled LDS row stride (33 even + 33 odd cols)
#define LCH 1122       // 17*66 floats per channel

typedef float v2f __attribute__((ext_vector_type(2)));

// ---------------- K0: transpose pointwise weights ---------------------------
__global__ __launch_bounds__(256) void k_cvt(
    const float* __restrict__ pw1, const float* __restrict__ pw2,
    const float* __restrict__ pw3, float* __restrict__ wb)
{
    int t = threadIdx.x;
    for (int i = t; i < 160;  i += 256) { int o = i / 5,  c = i % 5;  wb[W_PW1T + c*32 + o] = pw1[i]; }
    for (int i = t; i < 2048; i += 256) { int o = i >> 5, c = i & 31; wb[W_PW2T + c*64 + o] = pw2[i]; }
    for (int i = t; i < 4096; i += 256) { int o = i >> 6, c = i & 63; wb[W_PW3T + c*64 + o] = pw3[i]; }
}

// ---------------- K12: fused stage1+stage2, LDS-shared f1 tile ---------------
// (256,3): 3 blocks/CU measured best — 4th block thrashes L1 on phase-A flow
// window (34KB/block vs 32KB L1) and contends LDS ports; round-3 A/B showed
// (256,4) = +27us. Do not raise.
__global__ __launch_bounds__(256, 3) void k_fuse12(
    const float* __restrict__ flow, const float* __restrict__ dw1,
    const float* __restrict__ b1, const float* __restrict__ dw2,
    const float* __restrict__ b2, const float* __restrict__ wb,
    float* __restrict__ out)
{
    __shared__ float f1buf[8 * LCH];   // 35,904 B

    const int t = threadIdx.x;
    const int bid = blockIdx.x;
    const int b = bid / TILES_PB;
    const int tile = bid - b * TILES_PB;
    const int oh0 = (tile / TILES_W) * TH;
    const int ow0 = (tile % TILES_W) * TW;

    const float sx = 2.f / (W0 - 1), sy = 2.f / (H0 - 1);

    // ---- uniform closed-form coefficients for coord-channel convs ----
    float cs2[3], rs3[3], cs4[3], rs4[3];
    #pragma unroll
    for (int k = 0; k < 3; k++) {
        cs2[k] = dw1[18+k]   + dw1[21+k]   + dw1[24+k];
        rs3[k] = dw1[27+3*k] + dw1[28+3*k] + dw1[29+3*k];
        cs4[k] = dw1[36+k]   + dw1[39+k]   + dw1[42+k];
        rs4[k] = dw1[36+3*k] + dw1[37+3*k] + dw1[38+3*k];
    }
    const float ax2 = 2.f * sx, ay2 = 2.f * sy;
    float ex[3], fyc[3];
    #pragma unroll
    for (int k = 0; k < 3; k++) { ex[k] = sx*(float)(k-1) - 1.f; fyc[k] = sy*(float)(k-1) - 1.f; }
    const float AX1 = ax2*(cs2[0]+cs2[1]+cs2[2]);
    const float AX0 = cs2[0]*ex[0]+cs2[1]*ex[1]+cs2[2]*ex[2];
    const float AY1 = ay2*(rs3[0]+rs3[1]+rs3[2]);
    const float AY0 = rs3[0]*fyc[0]+rs3[1]*fyc[1]+rs3[2]*fyc[2];
    const float GX2 = ax2*ax2*(cs4[0]+cs4[1]+cs4[2]);
    const float GX1 = 2.f*ax2*(cs4[0]*ex[0]+cs4[1]*ex[1]+cs4[2]*ex[2]);
    const float GX0 = cs4[0]*ex[0]*ex[0]+cs4[1]*ex[1]*ex[1]+cs4[2]*ex[2]*ex[2];
    const float GY2 = ay2*ay2*(rs4[0]+rs4[1]+rs4[2]);
    const float GY1 = 2.f*ay2*(rs4[0]*fyc[0]+rs4[1]*fyc[1]+rs4[2]*fyc[2]);
    const float GY0 = rs4[0]*fyc[0]*fyc[0]+rs4[1]*fyc[1]*fyc[1]+rs4[2]*fyc[2]*fyc[2];

    // ---- Phase A: d-vectors for 5 f1 pixels/thread ----
    float dd[5][5];
    float vmf[5];
    int   widx[5];
    const float* fb0 = flow + (size_t)(b*2) * (H0*W0);
    const float* fb1 = fb0 + (size_t)(H0*W0);

    #pragma unroll
    for (int i = 0; i < 5; i++) {
        int p = t + i*256; if (p > NP-1) p = NP-1;      // only i==4 clamps
        int tr = p / F1COLS;
        int tc = p - tr * F1COLS;
        widx[i] = tr*LROW + (tc & 1)*33 + (tc >> 1);    // parity-split swizzle
        int fr = 2*oh0 - 1 + tr;
        int fc = 2*ow0 - 1 + tc;
        vmf[i] = (fr >= 0 && fc >= 0) ? 1.f : 0.f;
        if (fr >= 1 && fc >= 1) {
            // interior: mask-free taps + closed-form coords
            const float* r0 = fb0 + (size_t)(2*fr - 1) * W0 + (2*fc - 1);
            const float* r1 = fb1 + (size_t)(2*fr - 1) * W0 + (2*fc - 1);
            float a0 = 0.f, a1 = 0.f;
            #pragma unroll
            for (int ky = 0; ky < 3; ky++)
                #pragma unroll
                for (int kx = 0; kx < 3; kx++) {
                    a0 = fmaf(dw1[ky*3+kx],   r0[ky*W0+kx], a0);
                    a1 = fmaf(dw1[9+ky*3+kx], r1[ky*W0+kx], a1);
                }
            dd[i][0] = a0; dd[i][1] = a1;
            float fcf = (float)fc, frf = (float)fr;
            dd[i][2] = fmaf(AX1, fcf, AX0);
            dd[i][3] = fmaf(AY1, frf, AY0);
            dd[i][4] = fmaf(fmaf(GX2, fcf, GX1), fcf, GX0)
                     + fmaf(fmaf(GY2, frf, GY1), frf, GY0);
        } else {
            // border: original general masked path
            int frc = fr < 0 ? 0 : fr, fcc = fc < 0 ? 0 : fc;
            int ih0 = 2*frc - 1, iw0 = 2*fcc - 1;
            float mh[3] = { ih0 >= 0 ? 1.f : 0.f, 1.f, 1.f };
            float mw[3] = { iw0 >= 0 ? 1.f : 0.f, 1.f, 1.f };
            int ihx[3] = { ih0 < 0 ? 0 : ih0, ih0 + 1, ih0 + 2 };
            int iwx[3] = { iw0 < 0 ? 0 : iw0, iw0 + 1, iw0 + 2 };
            float a0 = 0.f, a1 = 0.f;
            #pragma unroll
            for (int ky = 0; ky < 3; ky++) {
                const float* rp0 = fb0 + (size_t)ihx[ky] * W0;
                const float* rp1 = fb1 + (size_t)ihx[ky] * W0;
                #pragma unroll
                for (int kx = 0; kx < 3; kx++) {
                    float m = mh[ky]*mw[kx];
                    a0 = fmaf(dw1[ky*3+kx],   m * rp0[iwx[kx]], a0);
                    a1 = fmaf(dw1[9+ky*3+kx], m * rp1[iwx[kx]], a1);
                }
            }
            dd[i][0] = a0; dd[i][1] = a1;
            float axv = 0.f, ayv = 0.f, arv = 0.f;
            #pragma unroll
            for (int ky = 0; ky < 3; ky++) {
                float yv = fmaf((float)(ih0 + ky), sy, -1.f);
                #pragma unroll
                for (int kx = 0; kx < 3; kx++) {
                    float xv = fmaf((float)(iw0 + kx), sx, -1.f);
                    float m = mh[ky]*mw[kx];
                    axv = fmaf(dw1[18 + ky*3 + kx], m * xv, axv);
                    ayv = fmaf(dw1[27 + ky*3 + kx], m * yv, ayv);
                    arv = fmaf(dw1[36 + ky*3 + kx], m * (xv*xv + yv*yv), arv);
                }
            }
            dd[i][2] = axv; dd[i][3] = ayv; dd[i][4] = arv;
        }
    }

    // ---- chunked A2 (f1 -> LDS) + B (dw2 + pw2) ----
    v2f acc2[32];
    #pragma unroll
    for (int o = 0; o < 32; o++) acc2[o] = *(const v2f*)(b2 + 2*o);

    const int lr = t >> 5, lc = t & 31;        // this thread's f2 pixel in tile
    const int rbase = 2*lr*LROW + lc;          // swizzled LDS base for taps

    for (int cc = 0; cc < 4; cc++) {
        #pragma unroll
        for (int j = 0; j < 8; j++) {
            int c = cc*8 + j;
            float w10 = wb[W_PW1T + c];
            float w11 = wb[W_PW1T + 32 + c];
            float w12 = wb[W_PW1T + 64 + c];
            float w13 = wb[W_PW1T + 96 + c];
            float w14 = wb[W_PW1T + 128 + c];
            float bc = b1[c];
            #pragma unroll
            for (int i = 0; i < 5; i++) {
                float v = bc;
                v = fmaf(w10, dd[i][0], v);
                v = fmaf(w11, dd[i][1], v);
                v = fmaf(w12, dd[i][2], v);
                v = fmaf(w13, dd[i][3], v);
                v = fmaf(w14, dd[i][4], v);
                float f = v > 0.f ? v : (__expf(v) - 1.f);
                f *= vmf[i];                       // invalid f1 pixel -> 0
                if (i < 4)               f1buf[j*LCH + widx[i]] = f;
                else if (t < NP - 1024)  f1buf[j*LCH + widx[4]] = f;   // t < 81
            }
        }
        __syncthreads();
        #pragma unroll
        for (int j = 0; j < 8; j++) {
            int c = cc*8 + j;
            const float* w9 = dw2 + c*9;               // uniform
            const float* fp = f1buf + j*LCH + rbase;
            float dv = 0.f;
            #pragma unroll
            for (int r = 0; r < 3; r++) {
                // tap cols 2*lc+{0,1,2} -> swizzled offsets {0, 33, 1}
                dv = fmaf(w9[r*3+0], fp[r*LROW],      dv);
                dv = fmaf(w9[r*3+1], fp[r*LROW + 33], dv);
                dv = fmaf(w9[r*3+2], fp[r*LROW + 1],  dv);
            }
            const v2f* wr2 = (const v2f*)(wb + W_PW2T + c*64);  // uniform
            v2f dvv = { dv, dv };
            #pragma unroll
            for (int o = 0; o < 32; o++)
                acc2[o] = __builtin_elementwise_fma(wr2[o], dvv, acc2[o]);  // v_pk_fma_f32
        }
        __syncthreads();
    }

    const int oh = oh0 + lr, ow = ow0 + lc;
    size_t obase = ((size_t)b * 64) * (H2*W2) + (size_t)oh * W2 + ow;
    #pragma unroll
    for (int o = 0; o < 32; o++) {
        float va = acc2[o].x, vb2 = acc2[o].y;
        out[obase + (size_t)(2*o)   * (H2*W2)] = va  > 0.f ? va  : (__expf(va)  - 1.f);
        out[obase + (size_t)(2*o+1) * (H2*W2)] = vb2 > 0.f ? vb2 : (__expf(vb2) - 1.f);
    }
}

// ---------------- K3: dwsep3 + ELU, packed pw3 + 2-deep channel pipeline ----
// Two channels in flight: 18 independent scattered taps issue together and
// hoist above the previous pair's pk_fma block, hiding L2/L3 latency.
__global__ __launch_bounds__(256, 4) void k_stage3(
    const float* __restrict__ in, const float* __restrict__ dw3,
    const float* __restrict__ b3, const float* __restrict__ wb,
    float* __restrict__ out)
{
    int idx = blockIdx.x * 256 + threadIdx.x;     // 153,600 exact
    int ow = idx % W3; int tmp = idx / W3; int oh = tmp % H3; int b = tmp / H3;
    int ih0 = 2*oh - 1, iw0 = 2*ow - 1;
    float mh[3] = { ih0 >= 0 ? 1.f : 0.f, 1.f, 1.f };
    float mw[3] = { iw0 >= 0 ? 1.f : 0.f, 1.f, 1.f };
    int ihx[3] = { ih0 < 0 ? 0 : ih0, ih0 + 1, ih0 + 2 };
    int iwx[3] = { iw0 < 0 ? 0 : iw0, iw0 + 1, iw0 + 2 };
    float m9[9];
    int off[9];
    #pragma unroll
    for (int ky = 0; ky < 3; ky++)
        #pragma unroll
        for (int kx = 0; kx < 3; kx++) {
            m9[ky*3 + kx] = mh[ky] * mw[kx];
            off[ky*3 + kx] = ihx[ky]*W2 + iwx[kx];
        }

    v2f acc2[32];
    #pragma unroll
    for (int o = 0; o < 32; o++) acc2[o] = *(const v2f*)(b3 + 2*o);

    const float* inb = in + (size_t)b * F2_PB;
    for (int c = 0; c < 64; c += 2) {
        const float* g0 = inb + (size_t)c * (H2*W2);
        const float* g1 = g0 + (H2*W2);
        float t0[9], t1[9];
        #pragma unroll
        for (int p = 0; p < 9; p++) t0[p] = g0[off[p]];
        #pragma unroll
        for (int p = 0; p < 9; p++) t1[p] = g1[off[p]];

        const float* w90 = dw3 + c*9;              // uniform
        const float* w91 = w90 + 9;
        float dv0 = 0.f, dv1 = 0.f;
        #pragma unroll
        for (int p = 0; p < 9; p++) {
            dv0 = fmaf(w90[p], m9[p] * t0[p], dv0);
            dv1 = fmaf(w91[p], m9[p] * t1[p], dv1);
        }
        const v2f* wr0 = (const v2f*)(wb + W_PW3T + c*64);       // uniform
        const v2f* wr1 = (const v2f*)(wb + W_PW3T + (c+1)*64);
        v2f dvv0 = { dv0, dv0 }, dvv1 = { dv1, dv1 };
        #pragma unroll
        for (int o = 0; o < 32; o++) {
            acc2[o] = __builtin_elementwise_fma(wr0[o], dvv0, acc2[o]);  // v_pk_fma_f32
            acc2[o] = __builtin_elementwise_fma(wr1[o], dvv1, acc2[o]);
        }
    }

    size_t obase = ((size_t)b * 64) * (H3*W3) + (size_t)oh*W3 + ow;
    #pragma unroll
    for (int o = 0; o < 32; o++) {
        float va = acc2[o].x, vb2 = acc2[o].y;
        out[obase + (size_t)(2*o)  *(H3*W3)] = va  > 0.f ? va  : (__expf(va)  - 1.f);
        out[obase + (size_t)(2*o+1)*(H3*W3)] = vb2 > 0.f ? vb2 : (__expf(vb2) - 1.f);
    }
}

// ---------------- K4: attention pool + MLP + GRU head -----------------------
__global__ __launch_bounds__(1024) void k_head(
    const float* __restrict__ f3,
    const float* __restrict__ attn_w, const float* __restrict__ attn_b,
    const float* __restrict__ mlp1_w, const float* __restrict__ mlp1_b,
    const float* __restrict__ mlp2_w, const float* __restrict__ mlp2_b,
    const float* __restrict__ w_ih, const float* __restrict__ b_ih,
    const float* __restrict__ b_hh,
    const float* __restrict__ fc_w, const float* __restrict__ fc_b,
    float* __restrict__ out)
{
    const int N  = H3 * W3;   // 4800
    const int N4 = N / 4;     // 1200
    __shared__ float s_w[H3 * W3];
    __shared__ float s_attn[64];
    __shared__ float s_redm[16];
    __shared__ float s_reds[16];
    __shared__ float s_inv[1];
    __shared__ float s_pooled[64];
    __shared__ float s_h1[32];
    __shared__ float s_om[3];
    __shared__ float s_h[32];

    int t = threadIdx.x, b = blockIdx.x;
    int lane = t & 63, wid = t >> 6;   // 16 waves
    if (t < 64) s_attn[t] = attn_w[t];
    __syncthreads();

    const float4* fb4 = (const float4*)(f3 + (size_t)b * F3_PB);
    float ab = attn_b[0];

    float lmax = -1e30f;
    for (int n4 = t; n4 < N4; n4 += 1024) {
        float4 l = make_float4(ab, ab, ab, ab);
        #pragma unroll 8
        for (int c = 0; c < 64; c++) {
            float4 v = fb4[c * N4 + n4];
            float a = s_attn[c];
            l.x = fmaf(a, v.x, l.x); l.y = fmaf(a, v.y, l.y);
            l.z = fmaf(a, v.z, l.z); l.w = fmaf(a, v.w, l.w);
        }
        ((float4*)s_w)[n4] = l;
        lmax = fmaxf(lmax, fmaxf(fmaxf(l.x, l.y), fmaxf(l.z, l.w)));
    }
    #pragma unroll
    for (int off = 32; off; off >>= 1) lmax = fmaxf(lmax, __shfl_down(lmax, off, 64));
    if (lane == 0) s_redm[wid] = lmax;
    __syncthreads();
    {
        float m = s_redm[0];
        #pragma unroll
        for (int i = 1; i < 16; i++) m = fmaxf(m, s_redm[i]);
        lmax = m;
    }

    float lsum = 0.f;
    for (int n = t; n < N; n += 1024) { float e = __expf(s_w[n] - lmax); s_w[n] = e; lsum += e; }
    #pragma unroll
    for (int off = 32; off; off >>= 1) lsum += __shfl_down(lsum, off, 64);
    if (lane == 0) s_reds[wid] = lsum;
    __syncthreads();
    if (t == 0) {
        float s = 0.f;
        #pragma unroll
        for (int i = 0; i < 16; i++) s += s_reds[i];
        s_inv[0] = 1.f / s;
    }
    __syncthreads();
    float invS = s_inv[0];

    const float4* sw4 = (const float4*)s_w;
    for (int c = wid; c < 64; c += 16) {
        float s = 0.f;
        for (int i = lane; i < N4; i += 64) {
            float4 v = fb4[c * N4 + i];
            float4 w = sw4[i];
            s = fmaf(v.x, w.x, s); s = fmaf(v.y, w.y, s);
            s = fmaf(v.z, w.z, s); s = fmaf(v.w, w.w, s);
        }
        #pragma unroll
        for (int off = 32; off; off >>= 1) s += __shfl_down(s, off, 64);
        if (lane == 0) s_pooled[c] = s * invS;
    }
    __syncthreads();

    if (t < 32) {
        float a = mlp1_b[t];
        #pragma unroll 8
        for (int c = 0; c < 64; c++) a = fmaf(mlp1_w[t*64 + c], s_pooled[c], a);
        s_h1[t] = a > 0.f ? a : (__expf(a) - 1.f);
    }
    __syncthreads();
    if (t < 3) {
        float a = mlp2_b[t];
        for (int j = 0; j < 32; j++) a = fmaf(mlp2_w[t*32 + j], s_h1[j], a);
        s_om[t] = a;
    }
    __syncthreads();
    if (t < 32) {
        float gr = b_ih[t], gz = b_ih[32 + t], gn = b_ih[64 + t];
        #pragma unroll
        for (int k = 0; k < 3; k++) {
            float ok = s_om[k];
            gr = fmaf(w_ih[t*3 + k],        ok, gr);
            gz = fmaf(w_ih[(32 + t)*3 + k], ok, gz);
            gn = fmaf(w_ih[(64 + t)*3 + k], ok, gn);
        }
        float hr = b_hh[t], hz = b_hh[32 + t], hn = b_hh[64 + t];
        float r = 1.f / (1.f + __expf(-(gr + hr)));
        float z = 1.f / (1.f + __expf(-(gz + hz)));
        float nn = tanhf(gn + r * hn);
        s_h[t] = (1.f - z) * nn;
    }
    __syncthreads();
    if (t < 3) {
        float dl = fc_b[t];
        for (int j = 0; j < 32; j++) dl = fmaf(fc_w[t*32 + j], s_h[j], dl);
        out[b*3 + t] = s_om[t] + dl;
    }
}

// ---------------- host ----------------
extern "C" void kernel_launch(void* const* d_in, const int* in_sizes, int n_in,
                              void* d_out, int out_size, void* d_ws, size_t ws_size,
                              hipStream_t stream)
{
    const float* flow = (const float*)d_in[0];
    float* wb = (float*)d_ws;

    // layout: [wbuf][f2 all 32 batches][f3 all 32 batches] = 196.7 MB (ws >= 275 MB)
    float* f2 = (float*)((char*)d_ws + WBUF_BYTES);
    float* f3 = f2 + (size_t)32 * F2_PB;

    k_cvt<<<1, 256, 0, stream>>>(
        (const float*)d_in[2], (const float*)d_in[5], (const float*)d_in[8], wb);

    // fused stage1+stage2: one block per 32x8 f2 tile
    k_fuse12<<<32 * TILES_PB, 256, 0, stream>>>(
        flow, (const float*)d_in[1], (const float*)d_in[3],
        (const float*)d_in[4], (const float*)d_in[6], wb, f2);

    // stage3: one thread per f3 pixel
    k_stage3<<<(32*H3*W3)/256, 256, 0, stream>>>(
        f2, (const float*)d_in[7], (const float*)d_in[9], wb, f3);

    k_head<<<32, 1024, 0, stream>>>(f3,
        (const float*)d_in[10], (const float*)d_in[11],
        (const float*)d_in[12], (const float*)d_in[13],
        (const float*)d_in[14], (const float*)d_in[15],
        (const float*)d_in[16], (const float*)d_in[18],
        (const float*)d_in[19], (const float*)d_in[20],
        (const float*)d_in[21], (float*)d_out);
}

// Round 6
// 310.698 us; speedup vs baseline: 1.0854x; 1.0854x over previous
//
#include <hip/hip_runtime.h>
#include <hip/hip_bf16.h>

#define H0 480
#define W0 640
#define H1 240
#define W1 320
#define H2 120
#define W2 160
#define H3 60
#define W3 80

// fp32 weight buffer offsets (in floats) inside d_ws  (transposed pointwise copies)
#define W_PW1T  0      // 5*32  [cin*32+o]
#define W_PW2T  160    // 32*64 [cin*64+o]
#define W_PW3T  2208   // 64*64 [cin*64+o]
#define WBUF_BYTES 65536

#define F2_PB (64 * H2 * W2)   // 1,228,800
#define F3_PB (64 * H3 * W3)   //   307,200
#define N3    (H3 * W3)        //     4,800

// k_fuse12 tiling: each block computes a 32x8 f2-pixel tile via a shared f1 tile.
#define TH 8           // f2 tile height
#define TW 32          // f2 tile width
#define TILES_W 5      // W2/TW
#define TILES_H 15     // H2/TH
#define TILES_PB 75    // per batch
#define F1COLS 65      // 2*TW+1
#define NP 1105        // 17*65 f1 pixels per tile
#define LROW 66        // swizzled LDS row stride (33 even + 33 odd cols)
#define LCH 1122       // 17*66 floats per channel

typedef float v2f __attribute__((ext_vector_type(2)));

// ---------------- K0: transpose pointwise weights ---------------------------
__global__ __launch_bounds__(256) void k_cvt(
    const float* __restrict__ pw1, const float* __restrict__ pw2,
    const float* __restrict__ pw3, float* __restrict__ wb)
{
    int t = threadIdx.x;
    for (int i = t; i < 160;  i += 256) { int o = i / 5,  c = i % 5;  wb[W_PW1T + c*32 + o] = pw1[i]; }
    for (int i = t; i < 2048; i += 256) { int o = i >> 5, c = i & 31; wb[W_PW2T + c*64 + o] = pw2[i]; }
    for (int i = t; i < 4096; i += 256) { int o = i >> 6, c = i & 63; wb[W_PW3T + c*64 + o] = pw3[i]; }
}

// ---------------- K12: fused stage1+stage2, LDS-shared f1 tile ---------------
// (256,3): 3 blocks/CU measured best — 4th block thrashes L1 on phase-A flow
// window (34KB/block vs 32KB L1) and contends LDS ports; round-3 A/B showed
// (256,4) = +27us. Do not raise.
__global__ __launch_bounds__(256, 3) void k_fuse12(
    const float* __restrict__ flow, const float* __restrict__ dw1,
    const float* __restrict__ b1, const float* __restrict__ dw2,
    const float* __restrict__ b2, const float* __restrict__ wb,
    float* __restrict__ out)
{
    __shared__ float f1buf[8 * LCH];   // 35,904 B

    const int t = threadIdx.x;
    const int bid = blockIdx.x;
    const int b = bid / TILES_PB;
    const int tile = bid - b * TILES_PB;
    const int oh0 = (tile / TILES_W) * TH;
    const int ow0 = (tile % TILES_W) * TW;

    const float sx = 2.f / (W0 - 1), sy = 2.f / (H0 - 1);

    // ---- uniform closed-form coefficients for coord-channel convs ----
    float cs2[3], rs3[3], cs4[3], rs4[3];
    #pragma unroll
    for (int k = 0; k < 3; k++) {
        cs2[k] = dw1[18+k]   + dw1[21+k]   + dw1[24+k];
        rs3[k] = dw1[27+3*k] + dw1[28+3*k] + dw1[29+3*k];
        cs4[k] = dw1[36+k]   + dw1[39+k]   + dw1[42+k];
        rs4[k] = dw1[36+3*k] + dw1[37+3*k] + dw1[38+3*k];
    }
    const float ax2 = 2.f * sx, ay2 = 2.f * sy;
    float ex[3], fyc[3];
    #pragma unroll
    for (int k = 0; k < 3; k++) { ex[k] = sx*(float)(k-1) - 1.f; fyc[k] = sy*(float)(k-1) - 1.f; }
    const float AX1 = ax2*(cs2[0]+cs2[1]+cs2[2]);
    const float AX0 = cs2[0]*ex[0]+cs2[1]*ex[1]+cs2[2]*ex[2];
    const float AY1 = ay2*(rs3[0]+rs3[1]+rs3[2]);
    const float AY0 = rs3[0]*fyc[0]+rs3[1]*fyc[1]+rs3[2]*fyc[2];
    const float GX2 = ax2*ax2*(cs4[0]+cs4[1]+cs4[2]);
    const float GX1 = 2.f*ax2*(cs4[0]*ex[0]+cs4[1]*ex[1]+cs4[2]*ex[2]);
    const float GX0 = cs4[0]*ex[0]*ex[0]+cs4[1]*ex[1]*ex[1]+cs4[2]*ex[2]*ex[2];
    const float GY2 = ay2*ay2*(rs4[0]+rs4[1]+rs4[2]);
    const float GY1 = 2.f*ay2*(rs4[0]*fyc[0]+rs4[1]*fyc[1]+rs4[2]*fyc[2]);
    const float GY0 = rs4[0]*fyc[0]*fyc[0]+rs4[1]*fyc[1]*fyc[1]+rs4[2]*fyc[2]*fyc[2];

    // ---- Phase A: d-vectors for 5 f1 pixels/thread ----
    float dd[5][5];
    float vmf[5];
    int   widx[5];
    const float* fb0 = flow + (size_t)(b*2) * (H0*W0);
    const float* fb1 = fb0 + (size_t)(H0*W0);

    #pragma unroll
    for (int i = 0; i < 5; i++) {
        int p = t + i*256; if (p > NP-1) p = NP-1;      // only i==4 clamps
        int tr = p / F1COLS;
        int tc = p - tr * F1COLS;
        widx[i] = tr*LROW + (tc & 1)*33 + (tc >> 1);    // parity-split swizzle
        int fr = 2*oh0 - 1 + tr;
        int fc = 2*ow0 - 1 + tc;
        vmf[i] = (fr >= 0 && fc >= 0) ? 1.f : 0.f;
        if (fr >= 1 && fc >= 1) {
            // interior: mask-free taps + closed-form coords
            const float* r0 = fb0 + (size_t)(2*fr - 1) * W0 + (2*fc - 1);
            const float* r1 = fb1 + (size_t)(2*fr - 1) * W0 + (2*fc - 1);
            float a0 = 0.f, a1 = 0.f;
            #pragma unroll
            for (int ky = 0; ky < 3; ky++)
                #pragma unroll
                for (int kx = 0; kx < 3; kx++) {
                    a0 = fmaf(dw1[ky*3+kx],   r0[ky*W0+kx], a0);
                    a1 = fmaf(dw1[9+ky*3+kx], r1[ky*W0+kx], a1);
                }
            dd[i][0] = a0; dd[i][1] = a1;
            float fcf = (float)fc, frf = (float)fr;
            dd[i][2] = fmaf(AX1, fcf, AX0);
            dd[i][3] = fmaf(AY1, frf, AY0);
            dd[i][4] = fmaf(fmaf(GX2, fcf, GX1), fcf, GX0)
                     + fmaf(fmaf(GY2, frf, GY1), frf, GY0);
        } else {
            // border: original general masked path
            int frc = fr < 0 ? 0 : fr, fcc = fc < 0 ? 0 : fc;
            int ih0 = 2*frc - 1, iw0 = 2*fcc - 1;
            float mh[3] = { ih0 >= 0 ? 1.f : 0.f, 1.f, 1.f };
            float mw[3] = { iw0 >= 0 ? 1.f : 0.f, 1.f, 1.f };
            int ihx[3] = { ih0 < 0 ? 0 : ih0, ih0 + 1, ih0 + 2 };
            int iwx[3] = { iw0 < 0 ? 0 : iw0, iw0 + 1, iw0 + 2 };
            float a0 = 0.f, a1 = 0.f;
            #pragma unroll
            for (int ky = 0; ky < 3; ky++) {
                const float* rp0 = fb0 + (size_t)ihx[ky] * W0;
                const float* rp1 = fb1 + (size_t)ihx[ky] * W0;
                #pragma unroll
                for (int kx = 0; kx < 3; kx++) {
                    float m = mh[ky]*mw[kx];
                    a0 = fmaf(dw1[ky*3+kx],   m * rp0[iwx[kx]], a0);
                    a1 = fmaf(dw1[9+ky*3+kx], m * rp1[iwx[kx]], a1);
                }
            }
            dd[i][0] = a0; dd[i][1] = a1;
            float axv = 0.f, ayv = 0.f, arv = 0.f;
            #pragma unroll
            for (int ky = 0; ky < 3; ky++) {
                float yv = fmaf((float)(ih0 + ky), sy, -1.f);
                #pragma unroll
                for (int kx = 0; kx < 3; kx++) {
                    float xv = fmaf((float)(iw0 + kx), sx, -1.f);
                    float m = mh[ky]*mw[kx];
                    axv = fmaf(dw1[18 + ky*3 + kx], m * xv, axv);
                    ayv = fmaf(dw1[27 + ky*3 + kx], m * yv, ayv);
                    arv = fmaf(dw1[36 + ky*3 + kx], m * (xv*xv + yv*yv), arv);
                }
            }
            dd[i][2] = axv; dd[i][3] = ayv; dd[i][4] = arv;
        }
    }

    // ---- chunked A2 (f1 -> LDS) + B (dw2 + pw2) ----
    v2f acc2[32];
    #pragma unroll
    for (int o = 0; o < 32; o++) acc2[o] = *(const v2f*)(b2 + 2*o);

    const int lr = t >> 5, lc = t & 31;        // this thread's f2 pixel in tile
    const int rbase = 2*lr*LROW + lc;          // swizzled LDS base for taps

    for (int cc = 0; cc < 4; cc++) {
        #pragma unroll
        for (int j = 0; j < 8; j++) {
            int c = cc*8 + j;
            float w10 = wb[W_PW1T + c];
            float w11 = wb[W_PW1T + 32 + c];
            float w12 = wb[W_PW1T + 64 + c];
            float w13 = wb[W_PW1T + 96 + c];
            float w14 = wb[W_PW1T + 128 + c];
            float bc = b1[c];
            #pragma unroll
            for (int i = 0; i < 5; i++) {
                float v = bc;
                v = fmaf(w10, dd[i][0], v);
                v = fmaf(w11, dd[i][1], v);
                v = fmaf(w12, dd[i][2], v);
                v = fmaf(w13, dd[i][3], v);
                v = fmaf(w14, dd[i][4], v);
                float f = v > 0.f ? v : (__expf(v) - 1.f);
                f *= vmf[i];                       // invalid f1 pixel -> 0
                if (i < 4)               f1buf[j*LCH + widx[i]] = f;
                else if (t < NP - 1024)  f1buf[j*LCH + widx[4]] = f;   // t < 81
            }
        }
        __syncthreads();
        #pragma unroll
        for (int j = 0; j < 8; j++) {
            int c = cc*8 + j;
            const float* w9 = dw2 + c*9;               // uniform
            const float* fp = f1buf + j*LCH + rbase;
            float dv = 0.f;
            #pragma unroll
            for (int r = 0; r < 3; r++) {
                // tap cols 2*lc+{0,1,2} -> swizzled offsets {0, 33, 1}
                dv = fmaf(w9[r*3+0], fp[r*LROW],      dv);
                dv = fmaf(w9[r*3+1], fp[r*LROW + 33], dv);
                dv = fmaf(w9[r*3+2], fp[r*LROW + 1],  dv);
            }
            const v2f* wr2 = (const v2f*)(wb + W_PW2T + c*64);  // uniform
            v2f dvv = { dv, dv };
            #pragma unroll
            for (int o = 0; o < 32; o++)
                acc2[o] = __builtin_elementwise_fma(wr2[o], dvv, acc2[o]);  // v_pk_fma_f32
        }
        __syncthreads();
    }

    const int oh = oh0 + lr, ow = ow0 + lc;
    size_t obase = ((size_t)b * 64) * (H2*W2) + (size_t)oh * W2 + ow;
    #pragma unroll
    for (int o = 0; o < 32; o++) {
        float va = acc2[o].x, vb2 = acc2[o].y;
        out[obase + (size_t)(2*o)   * (H2*W2)] = va  > 0.f ? va  : (__expf(va)  - 1.f);
        out[obase + (size_t)(2*o+1) * (H2*W2)] = vb2 > 0.f ? vb2 : (__expf(vb2) - 1.f);
    }
}

// ---------------- K3: dwsep3 + ELU + fused attention logits ------------------
// Round-3 structure (packed pw3, no explicit pipeline — the 2-deep staging of
// round 4 cost +33us). New: the attn 1x1 logit dot is computed in the
// epilogue from the ELU'd channel values already in registers, eliminating
// k_head's entire first f3 read pass.
__global__ __launch_bounds__(256, 4) void k_stage3(
    const float* __restrict__ in, const float* __restrict__ dw3,
    const float* __restrict__ b3, const float* __restrict__ wb,
    const float* __restrict__ attn_w, const float* __restrict__ attn_b,
    float* __restrict__ out, float* __restrict__ lg)
{
    int idx = blockIdx.x * 256 + threadIdx.x;     // 153,600 exact
    int ow = idx % W3; int tmp = idx / W3; int oh = tmp % H3; int b = tmp / H3;
    int ih0 = 2*oh - 1, iw0 = 2*ow - 1;
    float mh[3] = { ih0 >= 0 ? 1.f : 0.f, 1.f, 1.f };
    float mw[3] = { iw0 >= 0 ? 1.f : 0.f, 1.f, 1.f };
    int ihx[3] = { ih0 < 0 ? 0 : ih0, ih0 + 1, ih0 + 2 };
    int iwx[3] = { iw0 < 0 ? 0 : iw0, iw0 + 1, iw0 + 2 };
    float m9[9];
    int off[9];
    #pragma unroll
    for (int ky = 0; ky < 3; ky++)
        #pragma unroll
        for (int kx = 0; kx < 3; kx++) {
            m9[ky*3 + kx] = mh[ky] * mw[kx];
            off[ky*3 + kx] = ihx[ky]*W2 + iwx[kx];
        }

    v2f acc2[32];
    #pragma unroll
    for (int o = 0; o < 32; o++) acc2[o] = *(const v2f*)(b3 + 2*o);

    const float* inb = in + (size_t)b * F2_PB;
    for (int c = 0; c < 64; c++) {
        const float* g = inb + (size_t)c * (H2*W2);
        const float* w9 = dw3 + c*9;               // uniform
        float dv = 0.f;
        #pragma unroll
        for (int p = 0; p < 9; p++)
            dv = fmaf(w9[p], m9[p] * g[off[p]], dv);
        const v2f* wr2 = (const v2f*)(wb + W_PW3T + c*64);  // uniform
        v2f dvv = { dv, dv };
        #pragma unroll
        for (int o = 0; o < 32; o++)
            acc2[o] = __builtin_elementwise_fma(wr2[o], dvv, acc2[o]);  // v_pk_fma_f32
    }

    size_t obase = ((size_t)b * 64) * (H3*W3) + (size_t)oh*W3 + ow;
    float logit = attn_b[0];
    #pragma unroll
    for (int o = 0; o < 32; o++) {
        float va = acc2[o].x, vb2 = acc2[o].y;
        float ea = va  > 0.f ? va  : (__expf(va)  - 1.f);
        float eb = vb2 > 0.f ? vb2 : (__expf(vb2) - 1.f);
        out[obase + (size_t)(2*o)  *(H3*W3)] = ea;
        out[obase + (size_t)(2*o+1)*(H3*W3)] = eb;
        logit = fmaf(attn_w[2*o],   ea, logit);    // attn_w: uniform s_loads
        logit = fmaf(attn_w[2*o+1], eb, logit);
    }
    lg[b*N3 + oh*W3 + ow] = logit;                 // coalesced per wave
}

// ---------------- K4a: per-batch softmax over logits ------------------------
// 32 blocks x 256 threads; 19.2KB/batch, L2-resident. Writes unnormalized e
// in place + invS[b] (same math order as the old fused head: sum*invS later).
__global__ __launch_bounds__(256) void k_softmax(
    float* __restrict__ lg, float* __restrict__ invs)
{
    int b = blockIdx.x, t = threadIdx.x;
    int lane = t & 63, wid = t >> 6;       // 4 waves
    __shared__ float sm[4], ss[4];
    float* base = lg + b*N3;

    float m = -1e30f;
    for (int n = t; n < N3; n += 256) m = fmaxf(m, base[n]);
    #pragma unroll
    for (int o = 32; o; o >>= 1) m = fmaxf(m, __shfl_down(m, o, 64));
    if (lane == 0) sm[wid] = m;
    __syncthreads();
    m = fmaxf(fmaxf(sm[0], sm[1]), fmaxf(sm[2], sm[3]));

    float s = 0.f;
    for (int n = t; n < N3; n += 256) {
        float e = __expf(base[n] - m);
        base[n] = e;
        s += e;
    }
    #pragma unroll
    for (int o = 32; o; o >>= 1) s += __shfl_down(s, o, 64);
    if (lane == 0) ss[wid] = s;
    __syncthreads();
    if (t == 0) invs[b] = 1.f / (ss[0] + ss[1] + ss[2] + ss[3]);
}

// ---------------- K4b: attention pooling, one block per (b,c) ---------------
// 2048 blocks x 256 threads = full-chip parallel reduction (old head used 32
// blocks = 1/8 of the chip for this read).
__global__ __launch_bounds__(256) void k_pool(
    const float* __restrict__ f3, const float* __restrict__ lg,
    const float* __restrict__ invs, float* __restrict__ pooled)
{
    int bc = blockIdx.x;           // b*64 + c
    int b = bc >> 6, c = bc & 63;
    int t = threadIdx.x, lane = t & 63, wid = t >> 6;
    __shared__ float sr[4];

    const float4* f = (const float4*)(f3 + (size_t)b * F3_PB + (size_t)c * N3);
    const float4* w = (const float4*)(lg + b*N3);

    float s = 0.f;
    for (int i = t; i < N3/4; i += 256) {
        float4 a = f[i], e = w[i];
        s = fmaf(a.x, e.x, s); s = fmaf(a.y, e.y, s);
        s = fmaf(a.z, e.z, s); s = fmaf(a.w, e.w, s);
    }
    #pragma unroll
    for (int o = 32; o; o >>= 1) s += __shfl_down(s, o, 64);
    if (lane == 0) sr[wid] = s;
    __syncthreads();
    if (t == 0) pooled[bc] = (sr[0] + sr[1] + sr[2] + sr[3]) * invs[b];
}

// ---------------- K4c: MLP + GRU tail, one wave per batch -------------------
__global__ __launch_bounds__(64) void k_tail(
    const float* __restrict__ pooled,
    const float* __restrict__ mlp1_w, const float* __restrict__ mlp1_b,
    const float* __restrict__ mlp2_w, const float* __restrict__ mlp2_b,
    const float* __restrict__ w_ih, const float* __restrict__ b_ih,
    const float* __restrict__ b_hh,
    const float* __restrict__ fc_w, const float* __restrict__ fc_b,
    float* __restrict__ out)
{
    __shared__ float s_pooled[64];
    __shared__ float s_h1[32];
    __shared__ float s_om[3];
    __shared__ float s_h[32];
    int t = threadIdx.x, b = blockIdx.x;

    s_pooled[t] = pooled[b*64 + t];
    __syncthreads();

    if (t < 32) {
        float a = mlp1_b[t];
        #pragma unroll 8
        for (int c = 0; c < 64; c++) a = fmaf(mlp1_w[t*64 + c], s_pooled[c], a);
        s_h1[t] = a > 0.f ? a : (__expf(a) - 1.f);
    }
    __syncthreads();
    if (t < 3) {
        float a = mlp2_b[t];
        for (int j = 0; j < 32; j++) a = fmaf(mlp2_w[t*32 + j], s_h1[j], a);
        s_om[t] = a;
    }
    __syncthreads();
    if (t < 32) {
        float gr = b_ih[t], gz = b_ih[32 + t], gn = b_ih[64 + t];
        #pragma unroll
        for (int k = 0; k < 3; k++) {
            float ok = s_om[k];
            gr = fmaf(w_ih[t*3 + k],        ok, gr);
            gz = fmaf(w_ih[(32 + t)*3 + k], ok, gz);
            gn = fmaf(w_ih[(64 + t)*3 + k], ok, gn);
        }
        float hr = b_hh[t], hz = b_hh[32 + t], hn = b_hh[64 + t];
        float r = 1.f / (1.f + __expf(-(gr + hr)));
        float z = 1.f / (1.f + __expf(-(gz + hz)));
        float nn = tanhf(gn + r * hn);
        s_h[t] = (1.f - z) * nn;
    }
    __syncthreads();
    if (t < 3) {
        float dl = fc_b[t];
        for (int j = 0; j < 32; j++) dl = fmaf(fc_w[t*32 + j], s_h[j], dl);
        out[b*3 + t] = s_om[t] + dl;
    }
}

// ---------------- host ----------------
extern "C" void kernel_launch(void* const* d_in, const int* in_sizes, int n_in,
                              void* d_out, int out_size, void* d_ws, size_t ws_size,
                              hipStream_t stream)
{
    const float* flow = (const float*)d_in[0];
    float* wb = (float*)d_ws;

    // layout: [wbuf][f2 x32][f3 x32][logits 32*4800][invS 32][pooled 32*64]
    float* f2     = (float*)((char*)d_ws + WBUF_BYTES);
    float* f3     = f2 + (size_t)32 * F2_PB;
    float* lg     = f3 + (size_t)32 * F3_PB;
    float* invs   = lg + (size_t)32 * N3;
    float* pooled = invs + 32;

    k_cvt<<<1, 256, 0, stream>>>(
        (const float*)d_in[2], (const float*)d_in[5], (const float*)d_in[8], wb);

    // fused stage1+stage2: one block per 32x8 f2 tile
    k_fuse12<<<32 * TILES_PB, 256, 0, stream>>>(
        flow, (const float*)d_in[1], (const float*)d_in[3],
        (const float*)d_in[4], (const float*)d_in[6], wb, f2);

    // stage3 + fused attn logits: one thread per f3 pixel
    k_stage3<<<(32*H3*W3)/256, 256, 0, stream>>>(
        f2, (const float*)d_in[7], (const float*)d_in[9], wb,
        (const float*)d_in[10], (const float*)d_in[11], f3, lg);

    k_softmax<<<32, 256, 0, stream>>>(lg, invs);

    k_pool<<<32*64, 256, 0, stream>>>(f3, lg, invs, pooled);

    k_tail<<<32, 64, 0, stream>>>(pooled,
        (const float*)d_in[12], (const float*)d_in[13],
        (const float*)d_in[14], (const float*)d_in[15],
        (const float*)d_in[16], (const float*)d_in[18],
        (const float*)d_in[19], (const float*)d_in[20],
        (const float*)d_in[21], (float*)d_out);
}